// Round 15
// baseline (184.367 us; speedup 1.0000x reference)
//
#include <hip/hip_runtime.h>
#include <hip/hip_bf16.h>

#define N_NODES 100000
#define N_EDGES 1600000
#define D 128
#define NBUCK 782        // ceil(100000/128) buckets of 128 rows
#define GB 391           // gemm super-blocks (2 buckets each)
#define G 320            // partition block-groups
#define EPB 5000         // edges per partition group (320*5000 = 1.6M)
#define CAPG 16          // slots per (bucket, group) window = 128B, line-aligned
#define WSLOT (G * CAPG) // 5120 slots per bucket in tmp
#define EBC 2240         // LDS sorted-edge capacity (mean 2048 + 4.2 sigma)
#define OCAP 8192        // overflow capacity (~100 expected)
#define SPT 10           // window slots per k_ss thread = WSLOT/512

typedef short  s8v  __attribute__((ext_vector_type(8)));
typedef float  f4v  __attribute__((ext_vector_type(4)));

__device__ __forceinline__ ushort f2bf(float f) {
    uint u = __float_as_uint(f);
    return (ushort)((u + 0x7FFFu + ((u >> 16) & 1u)) >> 16);
}
__device__ __forceinline__ float bflo(uint u) { return __uint_as_float(u << 16); }
__device__ __forceinline__ float bfhi(uint u) { return __uint_as_float(u & 0xFFFF0000u); }

// ---------------------------------------------------------------------------
// wt[n][k] = bf16(w[k][n]); zeroes overflow cursor
// ---------------------------------------------------------------------------
__global__ __launch_bounds__(256) void k_wt(const float* __restrict__ w,
                                            ushort* __restrict__ wt,
                                            int* __restrict__ ocur) {
    int i = blockIdx.x * 256 + threadIdx.x;
    if (i == 0) *ocur = 0;
    if (i < D * D) {
        int k = i >> 7, n = i & 127;
        wt[n * D + k] = f2bf(w[i]);
    }
}

// ---------------------------------------------------------------------------
// FUSED prep kernel (round-15): 391 gemm super-blocks (2 tiles each,
// Wt re-staged from L2 between tiles) + 320 part blocks = 711 blocks
// <= 1024 residency slots -> all blocks start at t=0, no dispatch tail.
// ---------------------------------------------------------------------------
__global__ __launch_bounds__(256, 4) void k_fuse(const float* __restrict__ x,
                                                 const ushort* __restrict__ wt,
                                                 ushort* __restrict__ supb,
                                                 const int* __restrict__ er,
                                                 const int* __restrict__ ec,
                                                 const float* __restrict__ ev,
                                                 int2* __restrict__ tmp,
                                                 int* __restrict__ counts,
                                                 int* __restrict__ ocur,
                                                 int4* __restrict__ ovf) {
    __shared__ __attribute__((aligned(16))) char smem[32768];

    const int t = (int)threadIdx.x;

    if (blockIdx.x < GB) {
        // ---------------- GEMM path: two 128-row tiles ---------------------
        char* Bl = smem;
        const int lane = t & 63;
        const int w    = t >> 6;
        const int4* g4 = (const int4*)wt;

        #pragma unroll 1
        for (int tile = 0; tile < 2; ++tile) {
            const int row0 = (blockIdx.x * 2 + tile) * 128;

            if (tile > 0) __syncthreads();   // epilogue reads of Bl done
            // stage (or re-stage) Wt -> LDS, swizzled
            #pragma unroll
            for (int i = 0; i < 8; ++i) {
                int idx = t + i * 256;
                int n = idx >> 4, c = idx & 15;
                *(int4*)(Bl + ((n * 256 + c * 16) ^ ((n & 7) << 4))) = g4[idx];
            }
            __syncthreads();

            f4v acc[2][8] = {};
            const int arow = row0 + w * 32 + (lane & 15);
            const int kb   = (lane >> 4) * 8;

            #pragma unroll
            for (int ks = 0; ks < 4; ++ks) {
                s8v a[2];
                #pragma unroll
                for (int m = 0; m < 2; ++m) {
                    int r = arow + m * 16;
                    float4 f0 = make_float4(0.f, 0.f, 0.f, 0.f);
                    float4 f1 = make_float4(0.f, 0.f, 0.f, 0.f);
                    if (r < N_NODES) {
                        const float4* p = (const float4*)(x + (size_t)r * D + ks * 32 + kb);
                        f0 = p[0];
                        f1 = p[1];
                    }
                    s8v av;
                    av[0] = (short)f2bf(f0.x); av[1] = (short)f2bf(f0.y);
                    av[2] = (short)f2bf(f0.z); av[3] = (short)f2bf(f0.w);
                    av[4] = (short)f2bf(f1.x); av[5] = (short)f2bf(f1.y);
                    av[6] = (short)f2bf(f1.z); av[7] = (short)f2bf(f1.w);
                    a[m] = av;
                }
                #pragma unroll
                for (int n = 0; n < 8; ++n) {
                    int brow = n * 16 + (lane & 15);
                    s8v b = *(s8v*)(Bl + ((brow * 256 + (ks * 32 + kb) * 2) ^ ((brow & 7) << 4)));
                    acc[0][n] = __builtin_amdgcn_mfma_f32_16x16x32_bf16(a[0], b, acc[0][n], 0, 0, 0);
                    acc[1][n] = __builtin_amdgcn_mfma_f32_16x16x32_bf16(a[1], b, acc[1][n], 0, 0, 0);
                }
            }

            __syncthreads();
            char* E = Bl + w * 8192;
            #pragma unroll
            for (int m = 0; m < 2; ++m)
                #pragma unroll
                for (int n = 0; n < 8; ++n)
                    #pragma unroll
                    for (int r = 0; r < 4; ++r) {
                        int rl  = m * 16 + ((lane >> 4) << 2) + r;
                        int col = n * 16 + (lane & 15);
                        *(ushort*)(E + ((rl * 256 + col * 2) ^ ((rl & 7) << 4))) =
                            f2bf(acc[m][n][r]);
                    }
            __syncthreads();
            #pragma unroll
            for (int i = 0; i < 8; ++i) {
                int idx = lane + i * 64;
                int rl = idx >> 4, c = idx & 15;
                int4 v = *(int4*)(E + ((rl * 256 + c * 16) ^ ((rl & 7) << 4)));
                int grow = row0 + w * 32 + rl;
                if (grow < N_NODES)
                    *(int4*)((char*)supb + (size_t)grow * 256 + c * 16) = v;
            }
        }
    } else {
        // ---------------- partition path (validated round 8/12/13) ---------
        int* cur = (int*)smem;
        const int g = blockIdx.x - GB;          // 0..G-1
        for (int i = t; i < NBUCK; i += 256) cur[i] = 0;
        __syncthreads();

        const int base = g * EPB;
        for (int i = t; i < EPB; i += 256) {
            int e = base + i;
            int   r = er[e];
            int   c = ec[e];
            float v = ev[e];
            int b = r >> 7;
            int p = atomicAdd(&cur[b], 1);
            if (p < CAPG) {
                tmp[(size_t)b * WSLOT + g * CAPG + p] =
                    make_int2(((r & 127) << 17) | c, __float_as_int(v));
            } else {
                int o = atomicAdd(ocur, 1);
                if (o < OCAP) ovf[o] = make_int4(r, c, __float_as_int(v), 0);
            }
        }
        __syncthreads();
        for (int i = t; i < NBUCK; i += 256) {
            int n = cur[i];
            counts[g * NBUCK + i] = (n > CAPG) ? CAPG : n;
        }
    }
}

// ---------------------------------------------------------------------------
// MERGED sort+spmm, single-pass (validated round 14's k_ss body, with the
// round-13 G/CAPG): one block (512 thr) per bucket; window slots staged in
// registers once; hist + scan + place into LDS es[]; then 8 waves x 16 rows
// run the half-wave / 8-deep gather spmm from LDS.
// ---------------------------------------------------------------------------
__global__ __launch_bounds__(512) void k_ss(const ushort* __restrict__ supb,
                                            const int2* __restrict__ tmp,
                                            const int* __restrict__ counts,
                                            const float* __restrict__ bias,
                                            float* __restrict__ out,
                                            int* __restrict__ ocur,
                                            int4* __restrict__ ovf) {
    __shared__ int wn[G];
    __shared__ int hist[128], ex[128], cur[128];
    __shared__ int2 es[EBC];
    const int tx = (int)threadIdx.x;
    const int b  = blockIdx.x;
    const int r0 = b << 7;

    for (int i = tx; i < G; i += 512) wn[i] = counts[i * NBUCK + b];
    if (tx < 128) { hist[tx] = 0; cur[tx] = 0; }
    __syncthreads();

    const int2* win = tmp + (size_t)b * WSLOT;

    // single pass: load held slots into registers (coalesced per k-step)
    int2 h[SPT];
    uint vmask = 0;
    #pragma unroll
    for (int k = 0; k < SPT; ++k) {
        int i = tx + k * 512;
        if ((i & (CAPG - 1)) < wn[i >> 4]) {
            h[k] = win[i];
            vmask |= (1u << k);
        }
    }
    #pragma unroll
    for (int k = 0; k < SPT; ++k)
        if (vmask & (1u << k)) atomicAdd(&hist[h[k].x >> 17], 1);
    __syncthreads();

    // scan over 128 rows -> exclusive starts (all threads hit barriers)
    int hv = (tx < 128) ? hist[tx] : 0;
    if (tx < 128) ex[tx] = hv;
    __syncthreads();
    for (int off = 1; off < 128; off <<= 1) {
        int t = 0;
        if (tx < 128 && tx >= off) t = ex[tx - off];
        __syncthreads();
        if (tx < 128) ex[tx] += t;
        __syncthreads();
    }
    if (tx < 128) ex[tx] -= hv;   // inclusive -> exclusive
    __syncthreads();

    // place into LDS es[] from registers, sorted by row; spill past EBC
    #pragma unroll
    for (int k = 0; k < SPT; ++k) {
        if (vmask & (1u << k)) {
            int2 t = h[k];
            int lr = t.x >> 17;
            int p  = ex[lr] + atomicAdd(&cur[lr], 1);
            if (p < EBC) {
                es[p] = make_int2(t.x & 0x1FFFF, t.y);
            } else {
                int oo = atomicAdd(ocur, 1);
                if (oo < OCAP)
                    ovf[oo] = make_int4(r0 + lr, t.x & 0x1FFFF, t.y, 0);
            }
        }
    }
    __syncthreads();

    // spmm phase: wave w handles rows w*16 .. w*16+15
    const int w    = tx >> 6;
    const int lane = tx & 63;
    const int sub  = lane >> 5;
    const int sl   = lane & 31;
    const uint2* S = (const uint2*)supb;

    float4 bb = make_float4(0.f, 0.f, 0.f, 0.f);
    if (sub == 0) bb = *(const float4*)(bias + 4 * sl);

    for (int rr = 0; rr < 16; ++rr) {
        const int lr = w * 16 + rr;
        const int gr = r0 + lr;
        if (gr >= N_NODES) break;     // rows are ordered; wave-uniform

        int j = ex[lr];
        int end = j + hist[lr];
        if (end > EBC) end = EBC;

        float4 acc = make_float4(0.f, 0.f, 0.f, 0.f);

        for (; j + 7 < end; j += 8) {
            int2 e0 = es[j + sub];
            int2 e1 = es[j + 2 + sub];
            int2 e2 = es[j + 4 + sub];
            int2 e3 = es[j + 6 + sub];
            uint2 s0 = S[(size_t)e0.x * 32 + sl];
            uint2 s1 = S[(size_t)e1.x * 32 + sl];
            uint2 s2 = S[(size_t)e2.x * 32 + sl];
            uint2 s3 = S[(size_t)e3.x * 32 + sl];
            float v0 = __int_as_float(e0.y), v1 = __int_as_float(e1.y);
            float v2 = __int_as_float(e2.y), v3 = __int_as_float(e3.y);
            acc.x += v0 * bflo(s0.x) + v1 * bflo(s1.x) + v2 * bflo(s2.x) + v3 * bflo(s3.x);
            acc.y += v0 * bfhi(s0.x) + v1 * bfhi(s1.x) + v2 * bfhi(s2.x) + v3 * bfhi(s3.x);
            acc.z += v0 * bflo(s0.y) + v1 * bflo(s1.y) + v2 * bflo(s2.y) + v3 * bflo(s3.y);
            acc.w += v0 * bfhi(s0.y) + v1 * bfhi(s1.y) + v2 * bfhi(s2.y) + v3 * bfhi(s3.y);
        }
        for (; j < end; j += 2) {
            int jj = j + sub;
            if (jj > end - 1) jj = end - 1;
            int2 e = es[jj];
            float v = (j + sub < end) ? __int_as_float(e.y) : 0.f;
            uint2 s = S[(size_t)e.x * 32 + sl];
            acc.x += v * bflo(s.x);
            acc.y += v * bfhi(s.x);
            acc.z += v * bflo(s.y);
            acc.w += v * bfhi(s.y);
        }

        acc.x += __shfl_xor(acc.x, 32);
        acc.y += __shfl_xor(acc.y, 32);
        acc.z += __shfl_xor(acc.z, 32);
        acc.w += __shfl_xor(acc.w, 32);

        if (sub == 0) {
            float4 o = make_float4(acc.x + bb.x, acc.y + bb.y,
                                   acc.z + bb.z, acc.w + bb.w);
            *(float4*)(out + (size_t)gr * D + 4 * sl) = o;
        }
    }
}

// ---------------------------------------------------------------------------
// Overflow cleanup (~100 edges): global atomics after k_ss.
// ---------------------------------------------------------------------------
__global__ __launch_bounds__(256) void k_ofl(const ushort* __restrict__ supb,
                                             const int4* __restrict__ ovf,
                                             const int* __restrict__ ocur,
                                             float* __restrict__ out) {
    int n = *ocur;
    if (n > OCAP) n = OCAP;
    const int lane = threadIdx.x & 63;
    const int stride = gridDim.x * 4;
    const uint* S = (const uint*)supb;
    for (int e = (blockIdx.x * 256 + threadIdx.x) >> 6; e < n; e += stride) {
        int4 rec = ovf[e];
        uint s = S[(size_t)rec.y * 64 + lane];
        float v = __int_as_float(rec.z);
        atomicAdd(&out[(size_t)rec.x * D + 2 * lane],     v * bflo(s));
        atomicAdd(&out[(size_t)rec.x * D + 2 * lane + 1], v * bfhi(s));
    }
}

extern "C" void kernel_launch(void* const* d_in, const int* in_sizes, int n_in,
                              void* d_out, int out_size, void* d_ws, size_t ws_size,
                              hipStream_t stream) {
    const float* x    = (const float*)d_in[0];
    const float* w    = (const float*)d_in[1];
    const float* bias = (const float*)d_in[2];
    const float* ev   = (const float*)d_in[3];
    const int*   er   = (const int*)d_in[4];
    const int*   ec   = (const int*)d_in[5];
    float* out = (float*)d_out;

    // workspace layout (16B aligned), ~58.8 MB (round-13 layout)
    char* ws = (char*)d_ws;
    ushort* supb   = (ushort*)(ws);                 // 25,600,000
    ushort* wt     = (ushort*)(ws + 25600000);      //     32,768
    int*    counts = (int*)   (ws + 25632768);      //  1,000,960
    int*    ocur   = (int*)   (ws + 26633728);      //         64
    int4*   ovf    = (int4*)  (ws + 26633792);      //    131,072
    int2*   tmp    = (int2*)  (ws + 26764864);      // 32,030,720

    k_wt  <<<64, 256, 0, stream>>>(w, wt, ocur);
    // fused: 391 gemm super-blocks (2 tiles each) || 320 partition blocks
    k_fuse<<<GB + G, 256, 0, stream>>>(x, wt, supb, er, ec, ev, tmp,
                                       counts, ocur, ovf);
    // merged per-bucket single-pass sort + spmm
    k_ss  <<<NBUCK, 512, 0, stream>>>(supb, tmp, counts, bias, out, ocur, ovf);
    k_ofl <<<16, 256, 0, stream>>>(supb, ovf, ocur, out);
}

// Round 16
// 121.005 us; speedup vs baseline: 1.5236x; 1.5236x over previous
//
#include <hip/hip_runtime.h>
#include <hip/hip_bf16.h>

#define N_NODES 100000
#define N_EDGES 1600000
#define D 128
#define NBUCK 782        // ceil(100000/128) buckets of 128 rows
#define G 320            // partition block-groups
#define EPB 5000         // edges per partition group (320*5000 = 1.6M)
#define CAPG 16          // slots per (bucket, group) window = 128B, line-aligned
#define WSLOT (G * CAPG) // 5120 slots per bucket in tmp
#define EBC 2240         // LDS sorted-edge capacity (mean 2048 + 4.2 sigma)
#define OCAP 8192        // overflow capacity (~100 expected)
#define SPT 10           // window slots per k_ss thread = WSLOT/512

typedef short  s8v  __attribute__((ext_vector_type(8)));
typedef float  f4v  __attribute__((ext_vector_type(4)));

__device__ __forceinline__ ushort f2bf(float f) {
    uint u = __float_as_uint(f);
    return (ushort)((u + 0x7FFFu + ((u >> 16) & 1u)) >> 16);
}
__device__ __forceinline__ float bflo(uint u) { return __uint_as_float(u << 16); }
__device__ __forceinline__ float bfhi(uint u) { return __uint_as_float(u & 0xFFFF0000u); }

// ---------------------------------------------------------------------------
// wt[n][k] = bf16(w[k][n]); zeroes overflow cursor
// ---------------------------------------------------------------------------
__global__ __launch_bounds__(256) void k_wt(const float* __restrict__ w,
                                            ushort* __restrict__ wt,
                                            int* __restrict__ ocur) {
    int i = blockIdx.x * 256 + threadIdx.x;
    if (i == 0) *ocur = 0;
    if (i < D * D) {
        int k = i >> 7, n = i & 127;
        wt[n * D + k] = f2bf(w[i]);
    }
}

// ---------------------------------------------------------------------------
// FUSED prep kernel (exact round-13 body, the proven best): blocks 0..781 =
// single-tile MFMA GEMM; blocks 782..1101 = block-private edge partition.
// ---------------------------------------------------------------------------
__global__ __launch_bounds__(256, 4) void k_fuse(const float* __restrict__ x,
                                                 const ushort* __restrict__ wt,
                                                 ushort* __restrict__ supb,
                                                 const int* __restrict__ er,
                                                 const int* __restrict__ ec,
                                                 const float* __restrict__ ev,
                                                 int2* __restrict__ tmp,
                                                 int* __restrict__ counts,
                                                 int* __restrict__ ocur,
                                                 int4* __restrict__ ovf) {
    __shared__ __attribute__((aligned(16))) char smem[32768];

    const int t = (int)threadIdx.x;

    if (blockIdx.x < NBUCK) {
        // ---------------- GEMM path ----------------------------------------
        char* Bl = smem;
        const int lane = t & 63;
        const int w    = t >> 6;
        const int row0 = blockIdx.x * 128;

        const int4* g4 = (const int4*)wt;
        #pragma unroll
        for (int i = 0; i < 8; ++i) {
            int idx = t + i * 256;
            int n = idx >> 4, c = idx & 15;
            *(int4*)(Bl + ((n * 256 + c * 16) ^ ((n & 7) << 4))) = g4[idx];
        }
        __syncthreads();

        f4v acc[2][8] = {};
        const int arow = row0 + w * 32 + (lane & 15);
        const int kb   = (lane >> 4) * 8;

        #pragma unroll
        for (int ks = 0; ks < 4; ++ks) {
            s8v a[2];
            #pragma unroll
            for (int m = 0; m < 2; ++m) {
                int r = arow + m * 16;
                float4 f0 = make_float4(0.f, 0.f, 0.f, 0.f);
                float4 f1 = make_float4(0.f, 0.f, 0.f, 0.f);
                if (r < N_NODES) {
                    const float4* p = (const float4*)(x + (size_t)r * D + ks * 32 + kb);
                    f0 = p[0];
                    f1 = p[1];
                }
                s8v av;
                av[0] = (short)f2bf(f0.x); av[1] = (short)f2bf(f0.y);
                av[2] = (short)f2bf(f0.z); av[3] = (short)f2bf(f0.w);
                av[4] = (short)f2bf(f1.x); av[5] = (short)f2bf(f1.y);
                av[6] = (short)f2bf(f1.z); av[7] = (short)f2bf(f1.w);
                a[m] = av;
            }
            #pragma unroll
            for (int n = 0; n < 8; ++n) {
                int brow = n * 16 + (lane & 15);
                s8v b = *(s8v*)(Bl + ((brow * 256 + (ks * 32 + kb) * 2) ^ ((brow & 7) << 4)));
                acc[0][n] = __builtin_amdgcn_mfma_f32_16x16x32_bf16(a[0], b, acc[0][n], 0, 0, 0);
                acc[1][n] = __builtin_amdgcn_mfma_f32_16x16x32_bf16(a[1], b, acc[1][n], 0, 0, 0);
            }
        }

        __syncthreads();
        char* E = Bl + w * 8192;
        #pragma unroll
        for (int m = 0; m < 2; ++m)
            #pragma unroll
            for (int n = 0; n < 8; ++n)
                #pragma unroll
                for (int r = 0; r < 4; ++r) {
                    int rl  = m * 16 + ((lane >> 4) << 2) + r;
                    int col = n * 16 + (lane & 15);
                    *(ushort*)(E + ((rl * 256 + col * 2) ^ ((rl & 7) << 4))) =
                        f2bf(acc[m][n][r]);
                }
        __syncthreads();
        #pragma unroll
        for (int i = 0; i < 8; ++i) {
            int idx = lane + i * 64;
            int rl = idx >> 4, c = idx & 15;
            int4 v = *(int4*)(E + ((rl * 256 + c * 16) ^ ((rl & 7) << 4)));
            int grow = row0 + w * 32 + rl;
            if (grow < N_NODES)
                *(int4*)((char*)supb + (size_t)grow * 256 + c * 16) = v;
        }
    } else {
        // ---------------- partition path -----------------------------------
        int* cur = (int*)smem;
        const int g = blockIdx.x - NBUCK;       // 0..G-1
        for (int i = t; i < NBUCK; i += 256) cur[i] = 0;
        __syncthreads();

        const int base = g * EPB;
        for (int i = t; i < EPB; i += 256) {
            int e = base + i;
            int   r = er[e];
            int   c = ec[e];
            float v = ev[e];
            int b = r >> 7;
            int p = atomicAdd(&cur[b], 1);
            if (p < CAPG) {
                tmp[(size_t)b * WSLOT + g * CAPG + p] =
                    make_int2(((r & 127) << 17) | c, __float_as_int(v));
            } else {
                int o = atomicAdd(ocur, 1);
                if (o < OCAP) ovf[o] = make_int4(r, c, __float_as_int(v), 0);
            }
        }
        __syncthreads();
        for (int i = t; i < NBUCK; i += 256) {
            int n = cur[i];
            counts[g * NBUCK + i] = (n > CAPG) ? CAPG : n;
        }
    }
}

// ---------------------------------------------------------------------------
// MERGED sort+spmm, single-pass (validated rounds 14/15): one block (512 thr)
// per bucket; window slots staged in registers once; hist + scan + place into
// LDS es[]; then 8 waves x 16 rows run the half-wave / 8-deep gather spmm.
// ---------------------------------------------------------------------------
__global__ __launch_bounds__(512) void k_ss(const ushort* __restrict__ supb,
                                            const int2* __restrict__ tmp,
                                            const int* __restrict__ counts,
                                            const float* __restrict__ bias,
                                            float* __restrict__ out,
                                            int* __restrict__ ocur,
                                            int4* __restrict__ ovf) {
    __shared__ int wn[G];
    __shared__ int hist[128], ex[128], cur[128];
    __shared__ int2 es[EBC];
    const int tx = (int)threadIdx.x;
    const int b  = blockIdx.x;
    const int r0 = b << 7;

    for (int i = tx; i < G; i += 512) wn[i] = counts[i * NBUCK + b];
    if (tx < 128) { hist[tx] = 0; cur[tx] = 0; }
    __syncthreads();

    const int2* win = tmp + (size_t)b * WSLOT;

    // single pass: load held slots into registers (coalesced per k-step)
    int2 h[SPT];
    uint vmask = 0;
    #pragma unroll
    for (int k = 0; k < SPT; ++k) {
        int i = tx + k * 512;
        if ((i & (CAPG - 1)) < wn[i >> 4]) {
            h[k] = win[i];
            vmask |= (1u << k);
        }
    }
    #pragma unroll
    for (int k = 0; k < SPT; ++k)
        if (vmask & (1u << k)) atomicAdd(&hist[h[k].x >> 17], 1);
    __syncthreads();

    // scan over 128 rows -> exclusive starts (all threads hit barriers)
    int hv = (tx < 128) ? hist[tx] : 0;
    if (tx < 128) ex[tx] = hv;
    __syncthreads();
    for (int off = 1; off < 128; off <<= 1) {
        int t = 0;
        if (tx < 128 && tx >= off) t = ex[tx - off];
        __syncthreads();
        if (tx < 128) ex[tx] += t;
        __syncthreads();
    }
    if (tx < 128) ex[tx] -= hv;   // inclusive -> exclusive
    __syncthreads();

    // place into LDS es[] from registers, sorted by row; spill past EBC
    #pragma unroll
    for (int k = 0; k < SPT; ++k) {
        if (vmask & (1u << k)) {
            int2 t = h[k];
            int lr = t.x >> 17;
            int p  = ex[lr] + atomicAdd(&cur[lr], 1);
            if (p < EBC) {
                es[p] = make_int2(t.x & 0x1FFFF, t.y);
            } else {
                int oo = atomicAdd(ocur, 1);
                if (oo < OCAP)
                    ovf[oo] = make_int4(r0 + lr, t.x & 0x1FFFF, t.y, 0);
            }
        }
    }
    __syncthreads();

    // spmm phase: wave w handles rows w*16 .. w*16+15
    const int w    = tx >> 6;
    const int lane = tx & 63;
    const int sub  = lane >> 5;
    const int sl   = lane & 31;
    const uint2* S = (const uint2*)supb;

    float4 bb = make_float4(0.f, 0.f, 0.f, 0.f);
    if (sub == 0) bb = *(const float4*)(bias + 4 * sl);

    for (int rr = 0; rr < 16; ++rr) {
        const int lr = w * 16 + rr;
        const int gr = r0 + lr;
        if (gr >= N_NODES) break;     // rows are ordered; wave-uniform

        int j = ex[lr];
        int end = j + hist[lr];
        if (end > EBC) end = EBC;

        float4 acc = make_float4(0.f, 0.f, 0.f, 0.f);

        for (; j + 7 < end; j += 8) {
            int2 e0 = es[j + sub];
            int2 e1 = es[j + 2 + sub];
            int2 e2 = es[j + 4 + sub];
            int2 e3 = es[j + 6 + sub];
            uint2 s0 = S[(size_t)e0.x * 32 + sl];
            uint2 s1 = S[(size_t)e1.x * 32 + sl];
            uint2 s2 = S[(size_t)e2.x * 32 + sl];
            uint2 s3 = S[(size_t)e3.x * 32 + sl];
            float v0 = __int_as_float(e0.y), v1 = __int_as_float(e1.y);
            float v2 = __int_as_float(e2.y), v3 = __int_as_float(e3.y);
            acc.x += v0 * bflo(s0.x) + v1 * bflo(s1.x) + v2 * bflo(s2.x) + v3 * bflo(s3.x);
            acc.y += v0 * bfhi(s0.x) + v1 * bfhi(s1.x) + v2 * bfhi(s2.x) + v3 * bfhi(s3.x);
            acc.z += v0 * bflo(s0.y) + v1 * bflo(s1.y) + v2 * bflo(s2.y) + v3 * bflo(s3.y);
            acc.w += v0 * bfhi(s0.y) + v1 * bfhi(s1.y) + v2 * bfhi(s2.y) + v3 * bfhi(s3.y);
        }
        for (; j < end; j += 2) {
            int jj = j + sub;
            if (jj > end - 1) jj = end - 1;
            int2 e = es[jj];
            float v = (j + sub < end) ? __int_as_float(e.y) : 0.f;
            uint2 s = S[(size_t)e.x * 32 + sl];
            acc.x += v * bflo(s.x);
            acc.y += v * bfhi(s.x);
            acc.z += v * bflo(s.y);
            acc.w += v * bfhi(s.y);
        }

        acc.x += __shfl_xor(acc.x, 32);
        acc.y += __shfl_xor(acc.y, 32);
        acc.z += __shfl_xor(acc.z, 32);
        acc.w += __shfl_xor(acc.w, 32);

        if (sub == 0) {
            float4 o = make_float4(acc.x + bb.x, acc.y + bb.y,
                                   acc.z + bb.z, acc.w + bb.w);
            *(float4*)(out + (size_t)gr * D + 4 * sl) = o;
        }
    }
}

// ---------------------------------------------------------------------------
// Overflow cleanup (~100 edges): global atomics after k_ss.
// ---------------------------------------------------------------------------
__global__ __launch_bounds__(256) void k_ofl(const ushort* __restrict__ supb,
                                             const int4* __restrict__ ovf,
                                             const int* __restrict__ ocur,
                                             float* __restrict__ out) {
    int n = *ocur;
    if (n > OCAP) n = OCAP;
    const int lane = threadIdx.x & 63;
    const int stride = gridDim.x * 4;
    const uint* S = (const uint*)supb;
    for (int e = (blockIdx.x * 256 + threadIdx.x) >> 6; e < n; e += stride) {
        int4 rec = ovf[e];
        uint s = S[(size_t)rec.y * 64 + lane];
        float v = __int_as_float(rec.z);
        atomicAdd(&out[(size_t)rec.x * D + 2 * lane],     v * bflo(s));
        atomicAdd(&out[(size_t)rec.x * D + 2 * lane + 1], v * bfhi(s));
    }
}

extern "C" void kernel_launch(void* const* d_in, const int* in_sizes, int n_in,
                              void* d_out, int out_size, void* d_ws, size_t ws_size,
                              hipStream_t stream) {
    const float* x    = (const float*)d_in[0];
    const float* w    = (const float*)d_in[1];
    const float* bias = (const float*)d_in[2];
    const float* ev   = (const float*)d_in[3];
    const int*   er   = (const int*)d_in[4];
    const int*   ec   = (const int*)d_in[5];
    float* out = (float*)d_out;

    // workspace layout (16B aligned), ~58.8 MB (round-13 layout)
    char* ws = (char*)d_ws;
    ushort* supb   = (ushort*)(ws);                 // 25,600,000
    ushort* wt     = (ushort*)(ws + 25600000);      //     32,768
    int*    counts = (int*)   (ws + 25632768);      //  1,000,960
    int*    ocur   = (int*)   (ws + 26633728);      //         64
    int4*   ovf    = (int4*)  (ws + 26633792);      //    131,072
    int2*   tmp    = (int2*)  (ws + 26764864);      // 32,030,720

    k_wt  <<<64, 256, 0, stream>>>(w, wt, ocur);
    // fused: GEMM (blocks 0..781) || edge partition (blocks 782..1101)
    k_fuse<<<NBUCK + G, 256, 0, stream>>>(x, wt, supb, er, ec, ev, tmp,
                                          counts, ocur, ovf);
    // merged per-bucket single-pass sort + spmm
    k_ss  <<<NBUCK, 512, 0, stream>>>(supb, tmp, counts, bias, out, ocur, ovf);
    k_ofl <<<16, 256, 0, stream>>>(supb, ovf, ocur, out);
}